// Round 11
// baseline (1065.429 us; speedup 1.0000x reference)
//
#include <hip/hip_runtime.h>
#include <stdint.h>

// Problem constants
constexpr int BB = 64;     // batch
constexpr int SS = 512;    // seq len
constexpr int DD = 256;    // emb dim
constexpr int HH = 256;    // hidden
constexpr int NHH = 4;     // heads
constexpr int KK = 1024;   // NH*H recurrent input dim

// HARD FACTS (r2-r10): register residency is allocator roulette -- moderate
// demand gets spilled even when pinned (r10: 16 pinned uint4 -> 52 regs +
// scratch). LDS residency is DETERMINISTIC. Step time == streamed_bytes /
// 64 B/cyc (r7). Fence-free tagged exchange works at sub-us (r10); fenced
// release/acquire costs ~4us/step (r6). fp8/int8 weights break accuracy (r8).
//
// ROUND 11: v-form 4-CU split (r10) with (a) the whole 128 KB per-CU weight
// slab in LDS (no VGPR gamble, zero streamed bytes), (b) out_i = o_loc*4+n
// remap so z = quad shfl-reduce (no 3rd barrier), (c) exchange overlapped:
// publisher lanes (quad-base, t<256) publish c(s+1) while waves 4-6 poll
// peers concurrently. 2 barriers/step.
constexpr int TT = 512;

typedef _Float16 f16;
typedef _Float16 f16x2 __attribute__((ext_vector_type(2)));

__device__ inline float dot2p(uint32_t a, uint32_t b, float c) {
  f16x2 av = __builtin_bit_cast(f16x2, a);
  f16x2 bv = __builtin_bit_cast(f16x2, b);
#if defined(__has_builtin)
#if __has_builtin(__builtin_amdgcn_fdot2)
  return __builtin_amdgcn_fdot2(av, bv, c, false);
#else
  return c + (float)av.x * (float)bv.x + (float)av.y * (float)bv.y;
#endif
#else
  return c + (float)av.x * (float)bv.x + (float)av.y * (float)bv.y;
#endif
}

__device__ inline float dot8(uint4 w, uint4 a, float c) {
  c = dot2p(w.x, a.x, c);
  c = dot2p(w.y, a.y, c);
  c = dot2p(w.z, a.z, c);
  c = dot2p(w.w, a.w, c);
  return c;
}

__device__ inline uint32_t pack2(float a, float b) {
  f16x2 v;
  v.x = (f16)a;
  v.y = (f16)b;
  return __builtin_bit_cast(uint32_t, v);
}

__device__ inline float fast_tanh(float x) {
  x = fminf(fmaxf(x, -15.f), 15.f);
  float e = __expf(2.f * x);
  return 1.f - 2.f / (e + 1.f);
}

// ---------------------------------------------------------------------------
// Prep A1: pack Wh [256,1024] fp32 -> Wq f16 for the v-form matvec.
// Wq[(p*16 + m)*512 + t]: t -> out_i=t&255 (o_loc=out_i>>2, n=out_i&3),
// ch2=t>>8. Holds Wh[64p + o_loc][256n + 128*ch2 + 8m .. +8) as 8 f16.
// ---------------------------------------------------------------------------
__global__ void k_pack_wq(const float* __restrict__ Wh, uint4* __restrict__ Wq) {
  int gid = blockIdx.x * blockDim.x + threadIdx.x;  // 32768
  int p = gid >> 13;
  int m = (gid >> 9) & 15;
  int t = gid & 511;
  int out_i = t & 255, ch2 = t >> 8;
  int o_loc = out_i >> 2, n = out_i & 3;
  const float* s = Wh + (64 * p + o_loc) * KK + 256 * n + 128 * ch2 + 8 * m;
  uint4 w;
  w.x = pack2(s[0], s[1]);
  w.y = pack2(s[2], s[3]);
  w.z = pack2(s[4], s[5]);
  w.w = pack2(s[6], s[7]);
  Wq[gid] = w;
}

// ---------------------------------------------------------------------------
// Prep A2/A3: transpose src[r, C] (r in [0,256)) -> dst[c*256 + r]
// ---------------------------------------------------------------------------
__global__ void k_transpose8(const float* __restrict__ src, float* __restrict__ dst,
                             int C, int total) {
  int gid = blockIdx.x * blockDim.x + threadIdx.x;
  if (gid >= total) return;
  int r = gid & 255, c = gid >> 8;
  dst[gid] = src[r * C + c];
}

// ---------------------------------------------------------------------------
// Prep B: U[row, o] = emb[src[row]] @ Wi^T + bi + bh (f16). Blocks beyond
// input_len[b] skipped.
// ---------------------------------------------------------------------------
__global__ __launch_bounds__(256) void k_precompute_u(
    const int* __restrict__ src, const float* __restrict__ emb,
    const float* __restrict__ WiT, const float* __restrict__ bi,
    const float* __restrict__ bh, const int* __restrict__ input_len,
    f16* __restrict__ U) {
  const int row0 = blockIdx.x * 32;
  const int b = row0 >> 9;
  if ((row0 & 511) >= input_len[b]) return;
  __shared__ float xs[32 * 256];
  __shared__ int srcs[32];
  const int tid = threadIdx.x;
  if (tid < 32) srcs[tid] = src[row0 + tid];
  __syncthreads();
  for (int i = tid; i < 32 * 256; i += 256) {
    int r = i >> 8, d = i & 255;
    xs[i] = emb[srcs[r] * DD + d];
  }
  __syncthreads();
  const int o = tid;
  float acc[32];
#pragma unroll
  for (int r = 0; r < 32; ++r) acc[r] = 0.f;
  for (int d0 = 0; d0 < 256; d0 += 8) {
    float w[8];
#pragma unroll
    for (int j = 0; j < 8; ++j) w[j] = WiT[(d0 + j) * 256 + o];  // coalesced
#pragma unroll
    for (int r = 0; r < 32; ++r) {
      const float4* xp = (const float4*)(xs + r * 256 + d0);  // broadcast
      float4 x0 = xp[0], x1 = xp[1];
      acc[r] += x0.x * w[0] + x0.y * w[1] + x0.z * w[2] + x0.w * w[3] +
                x1.x * w[4] + x1.y * w[5] + x1.z * w[6] + x1.w * w[7];
    }
  }
  float bias = bi[o] + bh[o];
#pragma unroll
  for (int r = 0; r < 32; ++r)
    U[(size_t)(row0 + r) * HH + o] = (f16)(acc[r] + bias);
}

// ---------------------------------------------------------------------------
// Main recurrence (v-form): 4 WGs (512 thr) per batch, blockIdx = p*64 + b.
// Thread t: out_i = t&255 (o_loc=out_i>>2, n=out_i&3), ch2 = t>>8.
// All weights in LDS (128 KB). ~133 KB static LDS -> 1 WG/CU, full chip.
// ---------------------------------------------------------------------------
__global__ void __attribute__((amdgpu_flat_work_group_size(512, 512)))
k_recurrence(
    const uint4* __restrict__ Wq, const f16* __restrict__ U,
    const float* __restrict__ fix_src, const int* __restrict__ input_len,
    const float* __restrict__ fc1T, const float* __restrict__ fc1_b,
    const float* __restrict__ fc2_W, const float* __restrict__ fc2_b,
    float* __restrict__ out, uint32_t* __restrict__ Cex,
    float* __restrict__ FPg, int* __restrict__ Flg) {
  __shared__ uint4 wlds[16 * TT];           // 128 KB: whole per-CU slab
  __shared__ __align__(16) f16 cbuf[256];   // 512 B: c(s)
  __shared__ float partials[512];           // 2 KB
  __shared__ float hbuf[256];               // 1 KB
  uint4* cvec = (uint4*)cbuf;

  const int idx = blockIdx.x;
  const int b = idx & 63;
  const int p = idx >> 6;
  const int t = threadIdx.x;
  const int out_i = t & 255, ch2 = t >> 8;
  const int o_loc = out_i >> 2, n = out_i & 3;
  const bool is_pub = (t < 256) && ((t & 3) == 0);

  // one-time: weight slab global -> LDS (coalesced)
#pragma unroll
  for (int m = 0; m < 16; ++m)
    wlds[m * TT + t] = Wq[(p * 16 + m) * TT + t];

  const int len = input_len[b];
  const f16* Ub = U + (size_t)b * SS * HH;
  const float* fsb = fix_src + b * SS;

  float v = 0.f;      // v_n[64p+o_loc] on t<256
  float h = 0.f;      // h_n[64p+o_loc] on t<256
  float c_own = 0.f;  // publisher lanes: own c(s)

  // prologue: c(0) = tanh(U(0)); publish tag 1, parity 0; gather peers
  if (is_pub) {
    c_own = fast_tanh((float)Ub[64 * p + o_loc]);
    cbuf[64 * p + o_loc] = (f16)c_own;
    uint32_t dw = ((uint32_t)__builtin_bit_cast(
                       unsigned short, (f16)c_own) << 16) | 1u;
    __hip_atomic_store(&Cex[((0 * 64 + b) * 4 + p) * 64 + o_loc], dw,
                       __ATOMIC_RELAXED, __HIP_MEMORY_SCOPE_AGENT);
  } else if (t >= 256 && t < 448) {
    int q = (p + (t >> 6) - 3) & 3;  // waves 4,5,6 -> peers p+1,p+2,p+3
    int lane = t & 63;
    uint32_t* addr = &Cex[((0 * 64 + b) * 4 + q) * 64 + lane];
    uint32_t dw;
    do {
      dw = __hip_atomic_load(addr, __ATOMIC_RELAXED, __HIP_MEMORY_SCOPE_AGENT);
    } while ((dw & 0xffffu) != 1u);
    cbuf[64 * q + lane] = __builtin_bit_cast(f16, (unsigned short)(dw >> 16));
  }
  __syncthreads();

#pragma unroll 1
  for (int s = 0; s < len; ++s) {
    // matvec: (c(s) @ Wh_n^T)[64p+o_loc], split over ch2 halves
    float acc = 0.f;
    const uint4* ap = cvec + ch2 * 16;  // wave-uniform -> broadcast
    const uint4* wp = wlds + t;
#pragma unroll
    for (int m = 0; m < 16; ++m) acc = dot8(wp[m * TT], ap[m], acc);
    partials[t] = acc;
    __syncthreads();  // B2

    const bool last = (s + 1 >= len);
    if (t < 256) {
      float mval = partials[out_i] + partials[256 + out_i];
      float g = 1.f / (1.f + __expf((float)(3 * n) - fsb[s]));
      v = g * mval + (1.f - g) * v;
      // h update: c(s)[own col] from publisher lane of this quad
      float cprev = __shfl(c_own, 0, 4);
      h = g * cprev + (1.f - g) * h;
      // z(s)[o_loc] = quad sum of v
      float z = v + __shfl_xor(v, 1, 4);
      z = z + __shfl_xor(z, 2, 4);
      if (is_pub && !last) {
        float u1 = (float)Ub[(size_t)(s + 1) * HH + 64 * p + o_loc];
        float cn = fast_tanh(u1 + z);
        c_own = cn;
        cbuf[64 * p + o_loc] = (f16)cn;
        uint32_t dw = ((uint32_t)__builtin_bit_cast(
                           unsigned short, (f16)cn) << 16) |
                      (uint32_t)(s + 2);
        int par = (s + 1) & 1;
        __hip_atomic_store(&Cex[((par * 64 + b) * 4 + p) * 64 + o_loc], dw,
                           __ATOMIC_RELAXED, __HIP_MEMORY_SCOPE_AGENT);
      }
    } else if (t < 448 && !last) {
      // poll peers for c(s+1) concurrently with local phase-2 work
      int q = (p + (t >> 6) - 3) & 3;
      int lane = t & 63;
      int par = (s + 1) & 1;
      uint32_t* addr = &Cex[((par * 64 + b) * 4 + q) * 64 + lane];
      uint32_t want = (uint32_t)(s + 2);
      uint32_t dw;
      do {
        dw = __hip_atomic_load(addr, __ATOMIC_RELAXED,
                               __HIP_MEMORY_SCOPE_AGENT);
      } while ((dw & 0xffffu) != want);
      cbuf[64 * q + lane] = __builtin_bit_cast(f16, (unsigned short)(dw >> 16));
    }
    __syncthreads();  // B1: cbuf = c(s+1) complete
  }

  // ---- epilogue: fc1 partial over this CU's 256 h-entries, one-time sync
  if (t < 256) hbuf[out_i] = h;  // hbuf[l]: o_loc=l>>2, n=l&3, i=64p+o_loc
  __syncthreads();
  {
    float acc = 0.f;
#pragma unroll 4
    for (int r = 0; r < 128; ++r) {
      int l = ch2 * 128 + r;
      int kg = (l & 3) * 256 + 64 * p + (l >> 2);
      acc += hbuf[l] * fc1T[(size_t)kg * 256 + out_i];
    }
    partials[t] = acc;
  }
  __syncthreads();
  if (t < 256)
    FPg[(b * 4 + p) * 256 + out_i] = partials[out_i] + partials[256 + out_i];
  __syncthreads();  // barrier drains stores before flag
  if (t == 0)
    __hip_atomic_store(&Flg[b * 4 + p], 0x5A5A5A5A, __ATOMIC_RELEASE,
                       __HIP_MEMORY_SCOPE_AGENT);
  if (p != 0) return;
  if (t < 4 && t > 0) {
    while (__hip_atomic_load(&Flg[b * 4 + t], __ATOMIC_ACQUIRE,
                             __HIP_MEMORY_SCOPE_AGENT) != 0x5A5A5A5A) {
    }
  }
  __syncthreads();
  if (t < 256) {
    float pre = fc1_b[t];
#pragma unroll
    for (int q = 0; q < 4; ++q)
      pre += __hip_atomic_load(&FPg[(b * 4 + q) * 256 + t], __ATOMIC_RELAXED,
                               __HIP_MEMORY_SCOPE_AGENT);
    partials[t] = fast_tanh(pre);  // reuse partials as hid
  }
  __syncthreads();
  if (t < 64) {
    float p0 = 0.f, p1 = 0.f;
    for (int oi = t; oi < 256; oi += 64) {
      float hh = partials[oi];
      p0 += hh * fc2_W[oi];
      p1 += hh * fc2_W[256 + oi];
    }
#pragma unroll
    for (int off = 32; off; off >>= 1) {
      p0 += __shfl_down(p0, off);
      p1 += __shfl_down(p1, off);
    }
    if (t == 0) {
      out[b * 2 + 0] = p0 + fc2_b[0];
      out[b * 2 + 1] = p1 + fc2_b[1];
    }
  }
}

// ---------------------------------------------------------------------------
// Host launcher
// ws: [0,512K) Wq | [512K,768K) WiT | [768K,1792K) fc1T | [1792K,18176K) U
//     | [18176K,18304K) Cex | [18304K,18560K) FPg | [18560K,+1K) Flg
// Cex/Flg need no init: 0xAA poison never matches a tag (<=513) or the magic.
// ---------------------------------------------------------------------------
extern "C" void kernel_launch(void* const* d_in, const int* in_sizes, int n_in,
                              void* d_out, int out_size, void* d_ws, size_t ws_size,
                              hipStream_t stream) {
  const int* src = (const int*)d_in[0];
  const int* input_len = (const int*)d_in[1];
  const float* fix_src = (const float*)d_in[2];
  const float* emb = (const float*)d_in[3];
  const float* Wi = (const float*)d_in[4];
  const float* bi = (const float*)d_in[5];
  const float* Wh = (const float*)d_in[6];
  const float* bh = (const float*)d_in[7];
  const float* fc1_W = (const float*)d_in[8];
  const float* fc1_b = (const float*)d_in[9];
  const float* fc2_W = (const float*)d_in[10];
  const float* fc2_b = (const float*)d_in[11];
  float* out = (float*)d_out;

  char* ws = (char*)d_ws;
  uint4* Wq = (uint4*)(ws);                           // 512 KB
  float* WiT = (float*)(ws + (512ull << 10));         // 256 KB
  float* fc1T = (float*)(ws + (768ull << 10));        // 1 MB
  f16* U = (f16*)(ws + (1792ull << 10));              // 16 MB
  uint32_t* Cex = (uint32_t*)(ws + (18176ull << 10)); // 128 KB
  float* FPg = (float*)(ws + (18304ull << 10));       // 256 KB
  int* Flg = (int*)(ws + (18560ull << 10));           // 1 KB
  const size_t needed = (18561ull << 10);
  if (ws_size < needed) return;

  k_pack_wq<<<128, 256, 0, stream>>>(Wh, Wq);
  k_transpose8<<<(65536 + 255) / 256, 256, 0, stream>>>(Wi, WiT, 256, 65536);
  k_transpose8<<<(262144 + 255) / 256, 256, 0, stream>>>(fc1_W, fc1T, 1024, 262144);
  k_precompute_u<<<BB * SS / 32, 256, 0, stream>>>(src, emb, WiT, bi, bh,
                                                   input_len, U);
  k_recurrence<<<BB * 4, TT, 0, stream>>>(Wq, U, fix_src, input_len, fc1T,
                                          fc1_b, fc2_W, fc2_b, out, Cex, FPg,
                                          Flg);
}